// Round 1
// 1783.253 us; speedup vs baseline: 2.2038x; 2.2038x over previous
//
#include <hip/hip_runtime.h>

typedef _Float16 h8 __attribute__((ext_vector_type(8)));
typedef _Float16 h4 __attribute__((ext_vector_type(4)));
typedef float    f4 __attribute__((ext_vector_type(4)));
typedef unsigned u4 __attribute__((ext_vector_type(4)));

#define NT     512
#define OUT0   33554432   // 64*512*1024
#define SENT   0x7fc00000u   // qNaN sentinel: real h is always finite

__device__ __forceinline__ float sigm(float x)  { return 1.0f / (1.0f + __expf(-x)); }
__device__ __forceinline__ float tanhf_(float x){ float e = __expf(2.0f * x); return 1.0f - 2.0f / (e + 1.0f); }

// ---------------- prep kernels ----------------

__global__ __launch_bounds__(256) void xconv_k(const float* __restrict__ x, _Float16* __restrict__ x16) {
    size_t i = ((size_t)blockIdx.x * 256 + threadIdx.x) * 4;
    f4 v = *(const f4*)(x + i);
    h4 o; o[0] = (_Float16)v[0]; o[1] = (_Float16)v[1]; o[2] = (_Float16)v[2]; o[3] = (_Float16)v[3];
    *(h4*)(x16 + i) = o;
}

// wcat16[dir][p][k], p = j*4 + gate, k<512 -> Wih, else Whh
__global__ __launch_bounds__(256) void wconv_k(const float* __restrict__ Wih_f, const float* __restrict__ Whh_f,
                                               const float* __restrict__ Wih_b, const float* __restrict__ Whh_b,
                                               _Float16* __restrict__ wcat) {
    size_t e = (size_t)blockIdx.x * 256 + threadIdx.x;
    int k4  = (int)(e & 255);
    int p   = (int)((e >> 8) & 2047);
    int dir = (int)(e >> 19);
    int gate = p & 3, j = p >> 2;
    int k = k4 * 4;
    const float* Wih = dir ? Wih_b : Wih_f;
    const float* Whh = dir ? Whh_b : Whh_f;
    f4 v;
    if (k < 512) v = *(const f4*)&Wih[((size_t)gate * 512 + j) * 512 + k];
    else         v = *(const f4*)&Whh[((size_t)gate * 512 + j) * 512 + (k - 512)];
    h4 o; o[0] = (_Float16)v[0]; o[1] = (_Float16)v[1]; o[2] = (_Float16)v[2]; o[3] = (_Float16)v[3];
    *(h4*)&wcat[(((size_t)dir * 2048) + p) * 1024 + k] = o;
}

// h0 -> fp16 (read once at t=0 with normal cached loads)
__global__ __launch_bounds__(256) void inith_k(const float* __restrict__ enc_h, _Float16* __restrict__ h16) {
    int e = blockIdx.x * 256 + threadIdx.x;   // 0..65535
    float v = enc_h[e];
    int b = e >> 10, q = e & 1023, dir = q >> 9, j = q & 511;
    h16[((size_t)(dir * 64 + b)) * 512 + j] = (_Float16)v;
}

// pre-fill out with qNaN sentinel so consumers can poll data directly
__global__ __launch_bounds__(256) void fillnan_k(unsigned* __restrict__ o) {
    size_t i = ((size_t)blockIdx.x * 256 + threadIdx.x) * 4;
    u4 v; v[0] = SENT; v[1] = SENT; v[2] = SENT; v[3] = SENT;
    *(u4*)(o + i) = v;
}

// ---------------- persistent bidirectional LSTM scan ----------------
// 256 blocks (1/CU): bx = [dir(1)][mg(2)][ng(5)]. Block: M=16 batches, N=64 gate
// rows, K=1024; 4 waves split K (256 each). Weights pinned in VGPRs all 512 steps.
// Sync: NO flags. h(t) is stored f32 into `out` (unique address per step, sc0 sc1,
// fire-and-forget). Consumers poll exactly the fragments they need until no element
// equals the qNaN sentinel -> data-ready == data-loaded, ~1.5 coherent round trips
// per step instead of 4 (store-drain + flag-store + flag-poll + h-reload).
__global__ __launch_bounds__(256, 1) void lstm_persist(
    const _Float16* __restrict__ x16, const _Float16* __restrict__ wcat,
    const float* __restrict__ b_f, const float* __restrict__ b_b,
    const float* __restrict__ enc_c,
    const _Float16* __restrict__ h16,    // [2 dir][64][512] h0 only
    float* __restrict__ out, float* __restrict__ hseg, float* __restrict__ cseg)
{
    const int bx  = blockIdx.x;
    const int dir = bx >> 7, mg = (bx >> 5) & 3, ng = bx & 31;
    const int b0 = mg * 16, p0 = ng * 64, j0 = ng * 16;
    const int tid = threadIdx.x, lane = tid & 63, kw = tid >> 6;
    const int l15 = lane & 15, koff = (lane >> 4) * 8;

    __shared__ float gbuf[2][4][16][68];   // parity-double-buffered split-K partials

    // ---- one-time: B fragments into registers, pinned so they survive the loop ----
    f4 wx[4][4], wh[4][4];
    #pragma unroll
    for (int nt = 0; nt < 4; ++nt) {
        const _Float16* wrow = wcat + ((size_t)dir * 2048 + p0 + nt * 16 + l15) * 1024 + kw * 128 + koff;
        #pragma unroll
        for (int s = 0; s < 4; ++s) {
            wx[nt][s] = *(const f4*)(wrow + s * 32);
            wh[nt][s] = *(const f4*)(wrow + 512 + s * 32);
        }
    }
    #pragma unroll
    for (int nt = 0; nt < 4; ++nt)
        #pragma unroll
        for (int s = 0; s < 4; ++s) {
            asm volatile("" : "+v"(wx[nt][s]));
            asm volatile("" : "+v"(wh[nt][s]));
        }

    // ---- one-time: per-thread epilogue state (thread owns (b0+mb, j0+jj)) ----
    const int mb = tid >> 4, jj = tid & 15;
    const float* bias = dir ? b_b : b_f;
    const float bi = bias[0 * 512 + j0 + jj];
    const float bf = bias[1 * 512 + j0 + jj];
    const float bg = bias[2 * 512 + j0 + jj];
    const float bo = bias[3 * 512 + j0 + jj];
    float c = enc_c[(size_t)(b0 + mb) * 1024 + dir * 512 + j0 + jj];
    float hlast = 0.f;

    // per-lane A-fragment base pointers
    const _Float16* xbase = x16 + (size_t)(b0 + l15) * NT * 512 + kw * 128 + koff;

    // prefetch x_0 fragments
    f4 xf[4];
    {
        const _Float16* xp = xbase + (size_t)(dir ? (NT - 1) : 0) * 512;
        #pragma unroll
        for (int s = 0; s < 4; ++s) xf[s] = *(const f4*)(xp + s * 32);
    }

    for (int t = 0; t < NT; ++t) {
        const int tx = dir ? (NT - 1 - t) : t;

        // ---- x-part MFMAs (independent of h -> off the sync critical path) ----
        f4 acc[4];
        #pragma unroll
        for (int nt = 0; nt < 4; ++nt) { acc[nt][0] = 0.f; acc[nt][1] = 0.f; acc[nt][2] = 0.f; acc[nt][3] = 0.f; }
        #pragma unroll
        for (int s = 0; s < 4; ++s) {
            h8 a = __builtin_bit_cast(h8, xf[s]);
            #pragma unroll
            for (int nt = 0; nt < 4; ++nt)
                acc[nt] = __builtin_amdgcn_mfma_f32_16x16x32_f16(a, __builtin_bit_cast(h8, wx[nt][s]), acc[nt], 0, 0, 0);
        }
        // pin: keep x-MFMAs from sinking below the volatile poll asm
        #pragma unroll
        for (int nt = 0; nt < 4; ++nt) asm volatile("" : "+v"(acc[nt]));

        // ---- h A-fragments ----
        h8 hfr[4];
        if (t == 0) {
            const _Float16* hp = h16 + (size_t)dir * 64 * 512 + (size_t)(b0 + l15) * 512 + kw * 128 + koff;
            #pragma unroll
            for (int s = 0; s < 4; ++s) hfr[s] = *(const h8*)(hp + s * 32);
        } else {
            // poll h(t-1) straight out of `out` (f32) until no sentinel remains
            const int txp = dir ? (NT - t) : (t - 1);
            const unsigned* hp32 = (const unsigned*)(out
                + ((size_t)(b0 + l15) * NT + txp) * 1024 + (size_t)dir * 512 + kw * 128 + koff);
            u4 q0, q1, q2, q3, q4, q5, q6, q7;
            int ok;
            do {
                asm volatile(
                    "global_load_dwordx4 %0, %8, off sc0 sc1\n\t"
                    "global_load_dwordx4 %1, %8, off offset:16 sc0 sc1\n\t"
                    "global_load_dwordx4 %2, %8, off offset:128 sc0 sc1\n\t"
                    "global_load_dwordx4 %3, %8, off offset:144 sc0 sc1\n\t"
                    "global_load_dwordx4 %4, %8, off offset:256 sc0 sc1\n\t"
                    "global_load_dwordx4 %5, %8, off offset:272 sc0 sc1\n\t"
                    "global_load_dwordx4 %6, %8, off offset:384 sc0 sc1\n\t"
                    "global_load_dwordx4 %7, %8, off offset:400 sc0 sc1\n\t"
                    "s_waitcnt vmcnt(0)"
                    : "=&v"(q0), "=&v"(q1), "=&v"(q2), "=&v"(q3),
                      "=&v"(q4), "=&v"(q5), "=&v"(q6), "=&v"(q7)
                    : "v"(hp32) : "memory");
                ok = (q0[0] != SENT) & (q0[1] != SENT) & (q0[2] != SENT) & (q0[3] != SENT)
                   & (q1[0] != SENT) & (q1[1] != SENT) & (q1[2] != SENT) & (q1[3] != SENT)
                   & (q2[0] != SENT) & (q2[1] != SENT) & (q2[2] != SENT) & (q2[3] != SENT)
                   & (q3[0] != SENT) & (q3[1] != SENT) & (q3[2] != SENT) & (q3[3] != SENT)
                   & (q4[0] != SENT) & (q4[1] != SENT) & (q4[2] != SENT) & (q4[3] != SENT)
                   & (q5[0] != SENT) & (q5[1] != SENT) & (q5[2] != SENT) & (q5[3] != SENT)
                   & (q6[0] != SENT) & (q6[1] != SENT) & (q6[2] != SENT) & (q6[3] != SENT)
                   & (q7[0] != SENT) & (q7[1] != SENT) & (q7[2] != SENT) & (q7[3] != SENT);
            } while (!__all(ok));
            // f32 -> f16 in-register (same RTN cast the producer used before)
            f4 v0 = __builtin_bit_cast(f4, q0), v1 = __builtin_bit_cast(f4, q1);
            f4 v2 = __builtin_bit_cast(f4, q2), v3 = __builtin_bit_cast(f4, q3);
            f4 v4 = __builtin_bit_cast(f4, q4), v5 = __builtin_bit_cast(f4, q5);
            f4 v6 = __builtin_bit_cast(f4, q6), v7 = __builtin_bit_cast(f4, q7);
            #pragma unroll
            for (int e = 0; e < 4; ++e) {
                hfr[0][e] = (_Float16)v0[e]; hfr[0][4 + e] = (_Float16)v1[e];
                hfr[1][e] = (_Float16)v2[e]; hfr[1][4 + e] = (_Float16)v3[e];
                hfr[2][e] = (_Float16)v4[e]; hfr[2][4 + e] = (_Float16)v5[e];
                hfr[3][e] = (_Float16)v6[e]; hfr[3][4 + e] = (_Float16)v7[e];
            }
        }

        // ---- h-part MFMAs ----
        #pragma unroll
        for (int s = 0; s < 4; ++s)
            #pragma unroll
            for (int nt = 0; nt < 4; ++nt)
                acc[nt] = __builtin_amdgcn_mfma_f32_16x16x32_f16(hfr[s], __builtin_bit_cast(h8, wh[nt][s]), acc[nt], 0, 0, 0);

        // ---- prefetch x_{t+1} fragments (normal cached loads) ----
        if (t + 1 < NT) {
            const _Float16* xp = xbase + (size_t)(dir ? (NT - 2 - t) : (t + 1)) * 512;
            #pragma unroll
            for (int s = 0; s < 4; ++s) xf[s] = *(const f4*)(xp + s * 32);
        }

        // ---- cross-wave split-K reduction via LDS (parity buffer -> 1 barrier/step) ----
        float (*gb)[16][68] = gbuf[t & 1];
        #pragma unroll
        for (int nt = 0; nt < 4; ++nt)
            #pragma unroll
            for (int r = 0; r < 4; ++r)
                gb[kw][(lane >> 4) * 4 + r][nt * 16 + l15] = acc[nt][r];
        __syncthreads();

        // ---- gates + state update (thread = (mb, jj)) ----
        float gi = bi, gf = bf, gg = bg, go = bo;
        #pragma unroll
        for (int w = 0; w < 4; ++w) {
            gi += gb[w][mb][jj * 4 + 0];
            gf += gb[w][mb][jj * 4 + 1];
            gg += gb[w][mb][jj * 4 + 2];
            go += gb[w][mb][jj * 4 + 3];
        }
        float i_ = sigm(gi), f_ = sigm(gf), o_ = sigm(go), g_ = tanhf_(gg);
        c = f_ * c + i_ * g_;
        float h = o_ * tanhf_(c);
        hlast = h;

        // ---- publish h(t): single coherent f32 store, fire-and-forget ----
        {
            float* od = out + ((size_t)(b0 + mb) * NT + tx) * 1024 + (size_t)(dir * 512 + j0 + jj);
            asm volatile("global_store_dword %0, %1, off sc0 sc1" :: "v"(od), "v"(h) : "memory");
        }
    }

    asm volatile("s_waitcnt vmcnt(0)" ::: "memory");

    // ---- final h/c state ----
    hseg[(size_t)(b0 + mb) * 1024 + dir * 512 + j0 + jj] = hlast;
    cseg[(size_t)(b0 + mb) * 1024 + dir * 512 + j0 + jj] = c;
}

// ---------------- launcher ----------------

extern "C" void kernel_launch(void* const* d_in, const int* in_sizes, int n_in,
                              void* d_out, int out_size, void* d_ws, size_t ws_size,
                              hipStream_t stream) {
    const float* xin   = (const float*)d_in[0];
    const float* enc_h = (const float*)d_in[1];
    const float* enc_c = (const float*)d_in[2];
    const float* Wih_f = (const float*)d_in[3];
    const float* Whh_f = (const float*)d_in[4];
    const float* b_f   = (const float*)d_in[5];
    const float* Wih_b = (const float*)d_in[6];
    const float* Whh_b = (const float*)d_in[7];
    const float* b_b   = (const float*)d_in[8];

    float* out  = (float*)d_out;
    float* hseg = out + OUT0;          // final h [64,1024]
    float* cseg = hseg + 65536;        // final c [64,1024]

    const size_t X16_BYTES  = (size_t)64 * 512 * 512 * 2;        // 33,554,432
    const size_t WCAT_BYTES = (size_t)2 * 2048 * 1024 * 2;       //  8,388,608

    _Float16* x16  = (_Float16*)d_ws;
    _Float16* wcat = (_Float16*)((char*)d_ws + X16_BYTES);
    _Float16* h16  = (_Float16*)((char*)d_ws + X16_BYTES + WCAT_BYTES);

    xconv_k<<<dim3(16384), dim3(256), 0, stream>>>(xin, x16);
    wconv_k<<<dim3(4096), dim3(256), 0, stream>>>(Wih_f, Whh_f, Wih_b, Whh_b, wcat);
    inith_k<<<dim3(256), dim3(256), 0, stream>>>(enc_h, h16);
    fillnan_k<<<dim3(32768), dim3(256), 0, stream>>>((unsigned*)out);
    lstm_persist<<<dim3(256), dim3(256), 0, stream>>>(x16, wcat, b_f, b_b, enc_c,
                                                      h16, out, hseg, cseg);
}